// Round 5
// baseline (63.935 us; speedup 1.0000x reference)
//
#include <hip/hip_runtime.h>

// KalmanGain: B=262144, N=8, M=4, fp32.
// Round 5: R4 structure + counted-vmcnt pipeline (T4) + LDS 44->40KB.
//   Block = 128 threads (2 waves), 64 batches, 2 lanes/batch.
//   Sigma H^T = F Sp (H F)^T + Q H^T = G u + Q H^T, G = F Sp.
// LDS granule map (float4): F/Q [0,1024) | Sp [1024,2048) | H [2048,2560).
// R is loaded straight to registers (pair-broadcast, tiny).
// Schedule (per wave, vmcnt ops are wave-uniform):
//   issue F(8)+H(4)            -> 12 outstanding
//   issue Sp(8)                -> 20
//   vmcnt(8)+barrier           : F,H landed; Sp in flight
//   read fr,hs ; compute u ; pair-sum
//   vmcnt(4)+barrier           : Sp landed (F reads all done -> F buf dead)
//   issue Q(8) into F buf      ; compute G = fr@Sp, A = G@u ; issue R loads
//   vmcnt(0)+barrier           : Q,R landed
//   A += Qown@H^T ; S = H A + R (pair-sum) ; inv(S) ; KG ; store
// Raw s_barrier + asm waitcnt (memory clobber) + sched_barrier(0) -- NOT
// __syncthreads(), which would emit the full vmcnt(0) drain each phase.
// Swizzle (rule 21 both-sides): LDS slot (b,j) holds granule k = j ^ (b&mask).

#define NBB 64
#define THREADS 128

#define WAIT_BAR(N) do {                                        \
    asm volatile("s_waitcnt vmcnt(" #N ")" ::: "memory");       \
    __builtin_amdgcn_s_barrier();                               \
    __builtin_amdgcn_sched_barrier(0);                          \
} while (0)

__device__ __forceinline__ void gl_lds16(const float* src, float4* dst) {
    __builtin_amdgcn_global_load_lds(
        (const __attribute__((address_space(1))) unsigned int*)src,
        (__attribute__((address_space(3))) unsigned int*)dst,
        16, 0, 0);
}

__global__ __launch_bounds__(THREADS) void kalman_gain_kernel(
    const float* __restrict__ Fg, const float* __restrict__ Hg,
    const float* __restrict__ Spg, const float* __restrict__ Qg,
    const float* __restrict__ Rg, float* __restrict__ out, int nb)
{
    __shared__ float4 smem4[2560];   // 40960 B -> 4 blocks/CU

    const int tid  = threadIdx.x;
    const int wid  = tid >> 6;       // wave 0..1
    const int lane = tid & 63;
    const int b0   = blockIdx.x * NBB;

    // ---- issue F (8/wave) then H (4/wave) ----
    #pragma unroll
    for (int r = 0; r < 8; ++r) {
        int rr = 2 * r + wid;
        int s = (rr << 6) | lane;
        int b = s >> 4, j = s & 15, k = j ^ (b & 15);
        gl_lds16(Fg + (size_t)(b0 + b) * 64 + k * 4, smem4 + (rr << 6));
    }
    #pragma unroll
    for (int r = 0; r < 4; ++r) {
        int rr = 2 * r + wid;
        int s = (rr << 6) | lane;
        int b = s >> 3, j = s & 7, k = j ^ (b & 7);
        gl_lds16(Hg + (size_t)(b0 + b) * 32 + k * 4, smem4 + 2048 + (rr << 6));
    }
    // ---- issue Sp (8/wave) ----
    #pragma unroll
    for (int r = 0; r < 8; ++r) {
        int rr = 2 * r + wid;
        int s = (rr << 6) | lane;
        int b = s >> 4, j = s & 15, k = j ^ (b & 15);
        gl_lds16(Spg + (size_t)(b0 + b) * 64 + k * 4, smem4 + 1024 + (rr << 6));
    }

    WAIT_BAR(8);   // F,H landed; Sp (8 newest) may still be in flight

    const int b_loc = tid >> 1;      // 0..63
    const int p     = tid & 1;       // own rows 4p..4p+3
    const int bm15  = b_loc & 15;
    const int bm7   = b_loc & 7;

    // ---- hs[j][rl] = H[j][4p+rl] ----
    float hs[16];
    #pragma unroll
    for (int j = 0; j < 4; ++j) {
        float4 v = smem4[2048 + b_loc * 8 + ((2 * j + p) ^ bm7)];
        hs[j*4+0] = v.x; hs[j*4+1] = v.y; hs[j*4+2] = v.z; hs[j*4+3] = v.w;
    }

    // ---- fr = own 4 F rows [4][8] ----
    float fr[32];
    #pragma unroll
    for (int il = 0; il < 4; ++il) {
        #pragma unroll
        for (int hh = 0; hh < 2; ++hh) {
            int k = 8 * p + 2 * il + hh;
            float4 v = smem4[b_loc * 16 + (k ^ bm15)];
            fr[il*8 + hh*4 + 0] = v.x; fr[il*8 + hh*4 + 1] = v.y;
            fr[il*8 + hh*4 + 2] = v.z; fr[il*8 + hh*4 + 3] = v.w;
        }
    }

    // ---- u = (H F)^T [8][4]: own-row partial, pair-sum ----
    float u[32];
    #pragma unroll
    for (int x = 0; x < 32; ++x) u[x] = 0.f;
    #pragma unroll
    for (int il = 0; il < 4; ++il)
        #pragma unroll
        for (int k = 0; k < 8; ++k)
            #pragma unroll
            for (int j = 0; j < 4; ++j)
                u[k*4+j] += hs[j*4+il] * fr[il*8+k];
    #pragma unroll
    for (int x = 0; x < 32; ++x) u[x] += __shfl_xor(u[x], 1, 64);

    WAIT_BAR(4);   // Sp landed; every lane done reading F LDS -> F buf reusable

    // ---- issue Q (8/wave) into F's LDS slots (hidden under G/A compute) ----
    #pragma unroll
    for (int r = 0; r < 8; ++r) {
        int rr = 2 * r + wid;
        int s = (rr << 6) | lane;
        int b = s >> 4, j = s & 15, k = j ^ (b & 15);
        gl_lds16(Qg + (size_t)(b0 + b) * 64 + k * 4, smem4 + (rr << 6));
    }

    // ---- G = own F rows @ Sp  [4][8] (stream Sp from LDS) ----
    float G[32];
    #pragma unroll
    for (int x = 0; x < 32; ++x) G[x] = 0.f;
    #pragma unroll
    for (int k = 0; k < 8; ++k) {
        float4 s0 = smem4[1024 + b_loc * 16 + ((2*k    ) ^ bm15)];
        float4 s1 = smem4[1024 + b_loc * 16 + ((2*k + 1) ^ bm15)];
        float sp[8] = {s0.x,s0.y,s0.z,s0.w, s1.x,s1.y,s1.z,s1.w};
        #pragma unroll
        for (int il = 0; il < 4; ++il)
            #pragma unroll
            for (int c = 0; c < 8; ++c)
                G[il*8+c] += fr[il*8+k] * sp[c];
    }

    // ---- A = G @ u  [4][4] ----
    float A[16];
    #pragma unroll
    for (int il = 0; il < 4; ++il)
        #pragma unroll
        for (int j = 0; j < 4; ++j) {
            float acc = 0.f;
            #pragma unroll
            for (int k = 0; k < 8; ++k)
                acc += G[il*8+k] * u[k*4+j];
            A[il*4+j] = acc;
        }

    // ---- R direct to regs (pair-broadcast; latency hidden under Q drain) ----
    const float4* R4g = reinterpret_cast<const float4*>(Rg) + (size_t)(b0 + b_loc) * 4;
    float4 rr0 = R4g[0], rr1 = R4g[1], rr2 = R4g[2], rr3 = R4g[3];

    WAIT_BAR(0);   // Q and R landed

    // ---- A += Qown @ H^T ----
    float qo[32];
    #pragma unroll
    for (int il = 0; il < 4; ++il) {
        #pragma unroll
        for (int hh = 0; hh < 2; ++hh) {
            int k = 8 * p + 2 * il + hh;
            float4 v = smem4[b_loc * 16 + (k ^ bm15)];
            qo[il*8 + hh*4 + 0] = v.x; qo[il*8 + hh*4 + 1] = v.y;
            qo[il*8 + hh*4 + 2] = v.z; qo[il*8 + hh*4 + 3] = v.w;
        }
    }
    #pragma unroll
    for (int j = 0; j < 4; ++j) {
        float4 h0 = smem4[2048 + b_loc * 8 + ((2*j    ) ^ bm7)];
        float4 h1 = smem4[2048 + b_loc * 8 + ((2*j + 1) ^ bm7)];
        float hrow[8] = {h0.x,h0.y,h0.z,h0.w, h1.x,h1.y,h1.z,h1.w};
        #pragma unroll
        for (int il = 0; il < 4; ++il) {
            float acc = 0.f;
            #pragma unroll
            for (int k = 0; k < 8; ++k)
                acc += qo[il*8+k] * hrow[k];
            A[il*4+j] += acc;
        }
    }

    // ---- S = H A : own partial, pair-sum, + R (regs) ----
    float s[16];
    #pragma unroll
    for (int pi = 0; pi < 4; ++pi)
        #pragma unroll
        for (int q = 0; q < 4; ++q) {
            float acc = 0.f;
            #pragma unroll
            for (int il = 0; il < 4; ++il)
                acc += hs[pi*4+il] * A[il*4+q];
            s[pi*4+q] = acc;
        }
    #pragma unroll
    for (int x = 0; x < 16; ++x) s[x] += __shfl_xor(s[x], 1, 64);
    s[0]  += rr0.x; s[1]  += rr0.y; s[2]  += rr0.z; s[3]  += rr0.w;
    s[4]  += rr1.x; s[5]  += rr1.y; s[6]  += rr1.z; s[7]  += rr1.w;
    s[8]  += rr2.x; s[9]  += rr2.y; s[10] += rr2.z; s[11] += rr2.w;
    s[12] += rr3.x; s[13] += rr3.y; s[14] += rr3.z; s[15] += rr3.w;

    // ---- invert S (4x4 SPD), unrolled Gauss-Jordan ----
    float is[16] = {1.f,0.f,0.f,0.f, 0.f,1.f,0.f,0.f, 0.f,0.f,1.f,0.f, 0.f,0.f,0.f,1.f};
    #pragma unroll
    for (int c = 0; c < 4; ++c) {
        float pinv = 1.0f / s[c*4+c];
        #pragma unroll
        for (int k = 0; k < 4; ++k) { s[c*4+k] *= pinv; is[c*4+k] *= pinv; }
        #pragma unroll
        for (int r = 0; r < 4; ++r) {
            if (r != c) {
                float fac = s[r*4+c];
                #pragma unroll
                for (int k = 0; k < 4; ++k) {
                    s[r*4+k]  -= fac * s[c*4+k];
                    is[r*4+k] -= fac * is[c*4+k];
                }
            }
        }
    }

    // ---- KG own rows = A @ inv(S), store ----
    float4* outg = reinterpret_cast<float4*>(out) + (size_t)(b0 + b_loc) * 8 + p * 4;
    #pragma unroll
    for (int il = 0; il < 4; ++il) {
        float4 o;
        o.x = A[il*4+0]*is[0] + A[il*4+1]*is[4] + A[il*4+2]*is[8]  + A[il*4+3]*is[12];
        o.y = A[il*4+0]*is[1] + A[il*4+1]*is[5] + A[il*4+2]*is[9]  + A[il*4+3]*is[13];
        o.z = A[il*4+0]*is[2] + A[il*4+1]*is[6] + A[il*4+2]*is[10] + A[il*4+3]*is[14];
        o.w = A[il*4+0]*is[3] + A[il*4+1]*is[7] + A[il*4+2]*is[11] + A[il*4+3]*is[15];
        outg[il] = o;
    }
}

extern "C" void kernel_launch(void* const* d_in, const int* in_sizes, int n_in,
                              void* d_out, int out_size, void* d_ws, size_t ws_size,
                              hipStream_t stream) {
    const float* F  = (const float*)d_in[0];
    const float* H  = (const float*)d_in[1];
    const float* Sp = (const float*)d_in[2];
    const float* Q  = (const float*)d_in[3];
    const float* R  = (const float*)d_in[4];
    float* out = (float*)d_out;

    int nb = in_sizes[0] / 64;          // B = 262144 (divisible by 64)
    int blocks = nb / NBB;              // 4096
    kalman_gain_kernel<<<blocks, THREADS, 0, stream>>>(F, H, Sp, Q, R, out, nb);
}

// Round 6
// 51.621 us; speedup vs baseline: 1.2386x; 1.2386x over previous
//
#include <hip/hip_runtime.h>

// KalmanGain: B=262144, N=8, M=4, fp32.
// Round 6: R4's proven __syncthreads schedule + 4 lanes/batch for occupancy.
//   Block = 256 threads (4 waves), 64 batches, 4 lanes/batch (2 rows each).
//   Sigma H^T = F Sp (H F)^T + Q H^T = G u + Q H^T, G = F Sp.
// LDS (float4 granules): F/Q [0,1024) | Sp [1024,2048) | H [2048,2560) = 40KB
//   -> 4 blocks/CU x 4 waves = 16 waves/CU (50% occupancy ceiling; R4 was 15%).
// R: lane p loads granule 4b+p directly (coalesced), adds own row pre-butterfly.
// Swizzle (rule 21 both-sides): LDS slot (b,j) holds global granule k=j^(b&mask);
// reads XOR the same mask. gl_lds dest stays linear.
// Schedule (R4-proven, plain __syncthreads):
//   issue F,H,Sp staging + R reg load ; barrier(drain) ;
//   read fr,hs ; u = (HF)^T partial ; butterfly x2 ; barrier (F dead) ;
//   issue Q into F slots ; G = fr@Sp ; A = G@u ; barrier(drain Q) ;
//   A += Qown@H^T ; S = H A + R ; butterfly x2 ; inv(S) ; KG ; store.

#define NBB 64
#define THREADS 256

__device__ __forceinline__ void gl_lds16(const float* src, float4* dst) {
    __builtin_amdgcn_global_load_lds(
        (const __attribute__((address_space(1))) unsigned int*)src,
        (__attribute__((address_space(3))) unsigned int*)dst,
        16, 0, 0);
}

__global__ __launch_bounds__(THREADS) void kalman_gain_kernel(
    const float* __restrict__ Fg, const float* __restrict__ Hg,
    const float* __restrict__ Spg, const float* __restrict__ Qg,
    const float* __restrict__ Rg, float* __restrict__ out, int nb)
{
    __shared__ float4 smem4[2560];   // 40960 B

    const int tid  = threadIdx.x;
    const int wid  = tid >> 6;       // wave 0..3
    const int lane = tid & 63;
    const int b0   = blockIdx.x * NBB;

    // ---- issue staging: F (4/wave), H (2/wave), Sp (4/wave) ----
    #pragma unroll
    for (int r = 0; r < 4; ++r) {                // F: 1024 granules
        int rr = 4 * r + wid;
        int s = (rr << 6) | lane;
        int b = s >> 4, j = s & 15, k = j ^ (b & 15);
        gl_lds16(Fg + (size_t)(b0 + b) * 64 + k * 4, smem4 + (rr << 6));
    }
    #pragma unroll
    for (int r = 0; r < 2; ++r) {                // H: 512 granules
        int rr = 4 * r + wid;
        int s = (rr << 6) | lane;
        int b = s >> 3, j = s & 7, k = j ^ (b & 7);
        gl_lds16(Hg + (size_t)(b0 + b) * 32 + k * 4, smem4 + 2048 + (rr << 6));
    }
    #pragma unroll
    for (int r = 0; r < 4; ++r) {                // Sp: 1024 granules
        int rr = 4 * r + wid;
        int s = (rr << 6) | lane;
        int b = s >> 4, j = s & 15, k = j ^ (b & 15);
        gl_lds16(Spg + (size_t)(b0 + b) * 64 + k * 4, smem4 + 1024 + (rr << 6));
    }

    const int b_loc = tid >> 2;      // 0..63
    const int p     = tid & 3;       // owns global rows 2p, 2p+1
    const int bm15  = b_loc & 15;
    const int bm7   = b_loc & 7;

    // ---- R own row: lane p loads granule 4*b + p (fully coalesced) ----
    const float4 Rr = *(reinterpret_cast<const float4*>(Rg)
                        + (size_t)(b0 + b_loc) * 4 + p);

    __syncthreads();   // drains staging (vmcnt 0) + barrier

    // ---- hs[j][rl] = H[j][2p+rl], rl=0..1 (value select on p&1) ----
    float hs[8];
    #pragma unroll
    for (int j = 0; j < 4; ++j) {
        float4 v = smem4[2048 + b_loc * 8 + ((2 * j + (p >> 1)) ^ bm7)];
        hs[j*2+0] = (p & 1) ? v.z : v.x;
        hs[j*2+1] = (p & 1) ? v.w : v.y;
    }

    // ---- fr = own 2 F rows [2][8] (granules 4p..4p+3) ----
    float fr[16];
    #pragma unroll
    for (int i = 0; i < 4; ++i) {
        float4 v = smem4[b_loc * 16 + ((4 * p + i) ^ bm15)];
        fr[i*4+0] = v.x; fr[i*4+1] = v.y; fr[i*4+2] = v.z; fr[i*4+3] = v.w;
    }

    // ---- u = (H F)^T [8][4]: own-row partial, 2-stage butterfly ----
    float u[32];
    #pragma unroll
    for (int x = 0; x < 32; ++x) u[x] = 0.f;
    #pragma unroll
    for (int rl = 0; rl < 2; ++rl)
        #pragma unroll
        for (int k = 0; k < 8; ++k)
            #pragma unroll
            for (int j = 0; j < 4; ++j)
                u[k*4+j] += hs[j*2+rl] * fr[rl*8+k];
    #pragma unroll
    for (int x = 0; x < 32; ++x) u[x] += __shfl_xor(u[x], 1, 64);
    #pragma unroll
    for (int x = 0; x < 32; ++x) u[x] += __shfl_xor(u[x], 2, 64);

    __syncthreads();   // all lanes done reading F LDS -> F buffer reusable

    // ---- issue Q (4/wave) into F's LDS slots (hidden under G/A compute) ----
    #pragma unroll
    for (int r = 0; r < 4; ++r) {
        int rr = 4 * r + wid;
        int s = (rr << 6) | lane;
        int b = s >> 4, j = s & 15, k = j ^ (b & 15);
        gl_lds16(Qg + (size_t)(b0 + b) * 64 + k * 4, smem4 + (rr << 6));
    }

    // ---- G = own F rows @ Sp  [2][8] (stream Sp rows from LDS) ----
    float G[16];
    #pragma unroll
    for (int x = 0; x < 16; ++x) G[x] = 0.f;
    #pragma unroll
    for (int k = 0; k < 8; ++k) {
        float4 s0 = smem4[1024 + b_loc * 16 + ((2*k    ) ^ bm15)];
        float4 s1 = smem4[1024 + b_loc * 16 + ((2*k + 1) ^ bm15)];
        float sp[8] = {s0.x,s0.y,s0.z,s0.w, s1.x,s1.y,s1.z,s1.w};
        #pragma unroll
        for (int il = 0; il < 2; ++il)
            #pragma unroll
            for (int c = 0; c < 8; ++c)
                G[il*8+c] += fr[il*8+k] * sp[c];
    }

    // ---- A = G @ u  [2][4] ----
    float A[8];
    #pragma unroll
    for (int il = 0; il < 2; ++il)
        #pragma unroll
        for (int j = 0; j < 4; ++j) {
            float acc = 0.f;
            #pragma unroll
            for (int k = 0; k < 8; ++k)
                acc += G[il*8+k] * u[k*4+j];
            A[il*4+j] = acc;
        }

    __syncthreads();   // drains Q staging

    // ---- A += Qown @ H^T ----
    float qo[16];
    #pragma unroll
    for (int i = 0; i < 4; ++i) {
        float4 v = smem4[b_loc * 16 + ((4 * p + i) ^ bm15)];
        qo[i*4+0] = v.x; qo[i*4+1] = v.y; qo[i*4+2] = v.z; qo[i*4+3] = v.w;
    }
    #pragma unroll
    for (int j = 0; j < 4; ++j) {
        float4 h0 = smem4[2048 + b_loc * 8 + ((2*j    ) ^ bm7)];
        float4 h1 = smem4[2048 + b_loc * 8 + ((2*j + 1) ^ bm7)];
        float hrow[8] = {h0.x,h0.y,h0.z,h0.w, h1.x,h1.y,h1.z,h1.w};
        #pragma unroll
        for (int il = 0; il < 2; ++il) {
            float acc = 0.f;
            #pragma unroll
            for (int k = 0; k < 8; ++k)
                acc += qo[il*8+k] * hrow[k];
            A[il*4+j] += acc;
        }
    }

    // ---- S = H A + R: own partial (+own R row), 2-stage butterfly ----
    float s[16];
    #pragma unroll
    for (int pi = 0; pi < 4; ++pi) {
        float rrow[4] = {Rr.x, Rr.y, Rr.z, Rr.w};
        #pragma unroll
        for (int q = 0; q < 4; ++q) {
            float acc = (pi == p) ? rrow[q] : 0.f;   // own R row, added once
            #pragma unroll
            for (int il = 0; il < 2; ++il)
                acc += hs[pi*2+il] * A[il*4+q];
            s[pi*4+q] = acc;
        }
    }
    #pragma unroll
    for (int x = 0; x < 16; ++x) s[x] += __shfl_xor(s[x], 1, 64);
    #pragma unroll
    for (int x = 0; x < 16; ++x) s[x] += __shfl_xor(s[x], 2, 64);

    // ---- invert S (4x4 SPD), unrolled Gauss-Jordan ----
    float is[16] = {1.f,0.f,0.f,0.f, 0.f,1.f,0.f,0.f, 0.f,0.f,1.f,0.f, 0.f,0.f,0.f,1.f};
    #pragma unroll
    for (int c = 0; c < 4; ++c) {
        float pinv = 1.0f / s[c*4+c];
        #pragma unroll
        for (int k = 0; k < 4; ++k) { s[c*4+k] *= pinv; is[c*4+k] *= pinv; }
        #pragma unroll
        for (int r = 0; r < 4; ++r) {
            if (r != c) {
                float fac = s[r*4+c];
                #pragma unroll
                for (int k = 0; k < 4; ++k) {
                    s[r*4+k]  -= fac * s[c*4+k];
                    is[r*4+k] -= fac * is[c*4+k];
                }
            }
        }
    }

    // ---- KG own 2 rows = A @ inv(S); store (wave-contiguous) ----
    float4* outg = reinterpret_cast<float4*>(out)
                 + (size_t)(b0 + b_loc) * 8 + 2 * p;
    #pragma unroll
    for (int il = 0; il < 2; ++il) {
        float4 o;
        o.x = A[il*4+0]*is[0] + A[il*4+1]*is[4] + A[il*4+2]*is[8]  + A[il*4+3]*is[12];
        o.y = A[il*4+0]*is[1] + A[il*4+1]*is[5] + A[il*4+2]*is[9]  + A[il*4+3]*is[13];
        o.z = A[il*4+0]*is[2] + A[il*4+1]*is[6] + A[il*4+2]*is[10] + A[il*4+3]*is[14];
        o.w = A[il*4+0]*is[3] + A[il*4+1]*is[7] + A[il*4+2]*is[11] + A[il*4+3]*is[15];
        outg[il] = o;
    }
}

extern "C" void kernel_launch(void* const* d_in, const int* in_sizes, int n_in,
                              void* d_out, int out_size, void* d_ws, size_t ws_size,
                              hipStream_t stream) {
    const float* F  = (const float*)d_in[0];
    const float* H  = (const float*)d_in[1];
    const float* Sp = (const float*)d_in[2];
    const float* Q  = (const float*)d_in[3];
    const float* R  = (const float*)d_in[4];
    float* out = (float*)d_out;

    int nb = in_sizes[0] / 64;          // B = 262144 (divisible by 64)
    int blocks = nb / NBB;              // 4096
    kalman_gain_kernel<<<blocks, THREADS, 0, stream>>>(F, H, Sp, Q, R, out, nb);
}